// Round 1
// baseline (705.010 us; speedup 1.0000x reference)
//
#include <hip/hip_runtime.h>

#define WSZ 2048
#define NSINK 4

constexpr int Ld = 4096;
constexpr int Dd = 128;
constexpr int BQ = 64;
constexpr int BK = 64;
constexpr float SCALE = 0.08838834764831845f; // 1/sqrt(128)

typedef short bf16x8 __attribute__((ext_vector_type(8)));
typedef float f32x4 __attribute__((ext_vector_type(4)));

__device__ __forceinline__ unsigned short f2bf(float f) {
    unsigned u = __float_as_uint(f);
    u += 0x7FFFu + ((u >> 16) & 1u);
    return (unsigned short)(u >> 16);
}

// XOR-swizzled LDS offsets (element units). 16B-aligned frags, conflict-spread.
__device__ __forceinline__ int qk_off(int row, int d) {       // [64][128] bf16
    return row * 128 + (((d >> 3) ^ (row & 15)) << 3) + (d & 7);
}
__device__ __forceinline__ int vt_off(int drow, int key) {    // [128][64] bf16 (V^T)
    return drow * 64 + (((key >> 3) ^ (drow & 7)) << 3) + (key & 7);
}
__device__ __forceinline__ int p_off(int row, int key) {      // [16][64] bf16 per wave
    return row * 64 + (((key >> 3) ^ (row & 7)) << 3) + (key & 7);
}

__global__ __launch_bounds__(256, 2)
void swa_fwd(const float* __restrict__ Qg, const float* __restrict__ Kg,
             const float* __restrict__ Vg, float* __restrict__ Og) {
    __shared__ unsigned short Qs[BQ * Dd];
    __shared__ unsigned short Ks[BK * Dd];
    __shared__ unsigned short Vts[Dd * BK];
    __shared__ unsigned short Ps[4 * 16 * BK];

    const int tid  = threadIdx.x;
    const int w    = tid >> 6;
    const int lane = tid & 63;
    const int ml   = lane & 15;
    const int quad = lane >> 4;

    const int qtile = (int)(gridDim.x - 1u - blockIdx.x);  // longest blocks first
    const int q0 = qtile * BQ;
    const int bh = blockIdx.y;

    const size_t baseQ  = ((size_t)bh * Ld + q0) * Dd;
    const size_t baseKV = (size_t)bh * Ld * Dd;

    // ---- stage Q (fp32 -> bf16, swizzled) ----
    #pragma unroll
    for (int i = 0; i < 8; ++i) {
        int idx = tid + i * 256;          // 2048 float4 units
        int row = idx >> 5;
        int d0  = (idx & 31) << 2;
        const float4 v = *(const float4*)(Qg + baseQ + (size_t)row * Dd + d0);
        *(ushort4*)&Qs[qk_off(row, d0)] =
            make_ushort4(f2bf(v.x), f2bf(v.y), f2bf(v.z), f2bf(v.w));
    }

    float m_i[4], l_i[4];
    f32x4 o_acc[8];
    const f32x4 zero4 = {0.f, 0.f, 0.f, 0.f};
    #pragma unroll
    for (int r = 0; r < 4; ++r) { m_i[r] = -1e30f; l_i[r] = 0.f; }
    #pragma unroll
    for (int t = 0; t < 8; ++t) o_acc[t] = zero4;

    const int kmin = max(0, q0 - (WSZ - 1));
    const int kb_first = (kmin / BK) * BK;
    const bool sink_extra = (kb_first > 0);
    const int nwin = (q0 + BQ - kb_first) / BK;
    const int nch = nwin + (sink_extra ? 1 : 0);

    const int qbase = q0 + w * 16 + quad * 4;

    for (int ci = 0; ci < nch; ++ci) {
        const int kb = sink_extra ? (ci == 0 ? 0 : kb_first + (ci - 1) * BK)
                                  : kb_first + ci * BK;

        __syncthreads();   // protect previous chunk's LDS reads (and Q staging, iter 0)
        // ---- stage K (coalesced) ----
        #pragma unroll
        for (int i = 0; i < 8; ++i) {
            int idx = tid + i * 256;
            int row = idx >> 5;
            int d0  = (idx & 31) << 2;
            const float4 v = *(const float4*)(Kg + baseKV + (size_t)(kb + row) * Dd + d0);
            *(ushort4*)&Ks[qk_off(row, d0)] =
                make_ushort4(f2bf(v.x), f2bf(v.y), f2bf(v.z), f2bf(v.w));
        }
        // ---- stage V transposed (lane->key so LDS writes are conflict-free) ----
        {
            int r  = tid & 63;
            int dg = (tid >> 6) << 2;
            #pragma unroll
            for (int i = 0; i < 8; ++i) {
                int d0 = dg + i * 16;
                const float4 v = *(const float4*)(Vg + baseKV + (size_t)(kb + r) * Dd + d0);
                Vts[vt_off(d0 + 0, r)] = f2bf(v.x);
                Vts[vt_off(d0 + 1, r)] = f2bf(v.y);
                Vts[vt_off(d0 + 2, r)] = f2bf(v.z);
                Vts[vt_off(d0 + 3, r)] = f2bf(v.w);
            }
        }
        __syncthreads();

        // ---- S = Q K^T (16x64 per wave) ----
        f32x4 s[4];
        #pragma unroll
        for (int t = 0; t < 4; ++t) s[t] = zero4;
        #pragma unroll
        for (int k0 = 0; k0 < Dd; k0 += 32) {
            bf16x8 a = *(const bf16x8*)&Qs[qk_off(w * 16 + ml, k0 + quad * 8)];
            #pragma unroll
            for (int t = 0; t < 4; ++t) {
                bf16x8 b = *(const bf16x8*)&Ks[qk_off(t * 16 + ml, k0 + quad * 8)];
                s[t] = __builtin_amdgcn_mfma_f32_16x16x32_bf16(a, b, s[t], 0, 0, 0);
            }
        }

        // ---- mask + scale (sentinel -1e30 for disallowed) ----
        float pv[4][4];
        #pragma unroll
        for (int t = 0; t < 4; ++t) {
            const int kg = kb + t * 16 + ml;
            #pragma unroll
            for (int r = 0; r < 4; ++r) {
                const int qg = qbase + r;
                const bool ok = (kg <= qg) && ((kg + (WSZ - 1) >= qg) || (kg < NSINK));
                pv[t][r] = ok ? s[t][r] * SCALE : -1e30f;
            }
        }

        // ---- online softmax (per row; state replicated across quad's 16 lanes) ----
        float alpha[4];
        #pragma unroll
        for (int r = 0; r < 4; ++r) {
            float mx = fmaxf(fmaxf(pv[0][r], pv[1][r]), fmaxf(pv[2][r], pv[3][r]));
            #pragma unroll
            for (int off = 1; off < 16; off <<= 1) mx = fmaxf(mx, __shfl_xor(mx, off));
            const float mnew = fmaxf(m_i[r], mx);
            alpha[r] = __expf(m_i[r] - mnew);   // exp(0)=1 when both -1e30; l stays 0
            float rs = 0.f;
            #pragma unroll
            for (int t = 0; t < 4; ++t) {
                float p = (pv[t][r] == -1e30f) ? 0.f : __expf(pv[t][r] - mnew);
                pv[t][r] = p;
                rs += p;
            }
            #pragma unroll
            for (int off = 1; off < 16; off <<= 1) rs += __shfl_xor(rs, off);
            l_i[r] = alpha[r] * l_i[r] + rs;
            m_i[r] = mnew;
        }

        // ---- P -> LDS (C-layout -> A-layout transform), rescale O ----
        unsigned short* Pw = &Ps[w * 16 * BK];
        #pragma unroll
        for (int t = 0; t < 4; ++t)
            #pragma unroll
            for (int r = 0; r < 4; ++r)
                Pw[p_off(quad * 4 + r, t * 16 + ml)] = f2bf(pv[t][r]);
        #pragma unroll
        for (int dt = 0; dt < 8; ++dt)
            #pragma unroll
            for (int r = 0; r < 4; ++r)
                o_acc[dt][r] *= alpha[r];

        // ---- O += P V  (contraction over 64 keys = 2 MFMA k-steps) ----
        #pragma unroll
        for (int k0 = 0; k0 < BK; k0 += 32) {
            bf16x8 a = *(const bf16x8*)&Pw[p_off(ml, k0 + quad * 8)];
            #pragma unroll
            for (int dt = 0; dt < 8; ++dt) {
                bf16x8 b = *(const bf16x8*)&Vts[vt_off(dt * 16 + ml, k0 + quad * 8)];
                o_acc[dt] = __builtin_amdgcn_mfma_f32_16x16x32_bf16(a, b, o_acc[dt], 0, 0, 0);
            }
        }
    }

    // ---- epilogue: O /= l, store fp32 ----
    #pragma unroll
    for (int r = 0; r < 4; ++r) {
        const float inv = 1.f / l_i[r];
        const int qg = qbase + r;
        float* op = Og + ((size_t)bh * Ld + qg) * Dd + ml;
        #pragma unroll
        for (int dt = 0; dt < 8; ++dt)
            op[dt * 16] = o_acc[dt][r] * inv;
    }
}

extern "C" void kernel_launch(void* const* d_in, const int* in_sizes, int n_in,
                              void* d_out, int out_size, void* d_ws, size_t ws_size,
                              hipStream_t stream) {
    const float* q = (const float*)d_in[0];
    const float* k = (const float*)d_in[1];
    const float* v = (const float*)d_in[2];
    float* o = (float*)d_out;
    const int bhn = in_sizes[0] / (Ld * Dd);   // B*H = 32
    dim3 grid(Ld / BQ, bhn);
    swa_fwd<<<grid, dim3(256, 1, 1), 0, stream>>>(q, k, v, o);
}

// Round 2
// 427.845 us; speedup vs baseline: 1.6478x; 1.6478x over previous
//
#include <hip/hip_runtime.h>

constexpr int Ld = 4096;
constexpr int Dd = 128;
constexpr int BQ = 128;
constexpr int BK = 64;
constexpr int WSZ = 2048;
constexpr int NSINK = 4;
// 1/sqrt(128) * log2(e)  (exp2-domain softmax; common factor cancels exactly)
constexpr float QSCALE = 0.08838834764831845f * 1.4426950408889634f;

typedef short bf16x8 __attribute__((ext_vector_type(8)));
typedef float f32x4 __attribute__((ext_vector_type(4)));

#if defined(__has_builtin)
#if __has_builtin(__builtin_amdgcn_exp2f)
#define EXP2(x) __builtin_amdgcn_exp2f(x)
#endif
#endif
#ifndef EXP2
#define EXP2(x) exp2f(x)
#endif

// pack two fp32 -> bf16 pair (hi<<16 | lo), half-up rounding, 3 VALU ops.
__device__ __forceinline__ unsigned pkbf(float hi, float lo) {
    unsigned uh = __float_as_uint(hi) + 0x8000u;
    unsigned ul = __float_as_uint(lo) + 0x8000u;
    return __builtin_amdgcn_perm(uh, ul, 0x07060302u); // {uh[31:16], ul[31:16]}
}

// --- swizzled LDS offsets (ushort units) ---
__device__ __forceinline__ int rd_off(int row, int d) {    // [rows][128]
    return row * 128 + ((((d >> 3) ^ row) & 15) << 3) + (d & 7);
}
__device__ __forceinline__ int vt_off(int drow, int key) { // [128][64] (V^T)
    return drow * 64 + ((((key >> 3) ^ drow) & 7) << 3) + (key & 7);
}
__device__ __forceinline__ int p_off(int row, int key) {   // [16][64], b64-granular
    return row * 64 + ((((key >> 2) ^ ((row & 7) << 1)) & 15) << 2) + (key & 3);
}

__global__ __launch_bounds__(256, 2)
void swa_fwd(const float* __restrict__ Qg, const float* __restrict__ Kg,
             const float* __restrict__ Vg, float* __restrict__ Og) {
    __shared__ __align__(16) unsigned short smem[24576]; // 48 KB
    unsigned short* Ks  = smem;          // [64][128]
    unsigned short* Vts = smem + 8192;   // [128][64]
    unsigned short* Ps  = smem + 16384;  // 4 waves x 2 groups x [16][64]
    unsigned short* Qst = smem;          // [128][128] staging alias (32 KB)

    const int tid  = threadIdx.x;
    const int w    = tid >> 6;
    const int lane = tid & 63;
    const int ml   = lane & 15;
    const int quad = lane >> 4;

    const int qtile = (int)(gridDim.x - 1u - blockIdx.x); // longest first
    const int q0 = qtile * BQ;
    const int bh = blockIdx.y;

    const size_t baseQ  = ((size_t)bh * Ld + q0) * Dd;
    const size_t baseKV = (size_t)bh * Ld * Dd;

    // ---- stage Q (scaled, fp32->bf16) into LDS scratch ----
    #pragma unroll
    for (int i = 0; i < 16; ++i) {
        int idx = tid + i * 256;
        int row = idx >> 5;
        int d0  = (idx & 31) << 2;
        float4 v = *(const float4*)(Qg + baseQ + (size_t)row * Dd + d0);
        *(uint2*)&Qst[rd_off(row, d0)] =
            make_uint2(pkbf(v.y * QSCALE, v.x * QSCALE),
                       pkbf(v.w * QSCALE, v.z * QSCALE));
    }
    __syncthreads();

    // ---- Q B-fragments to registers: qf[group][k0]  (B[n=q=ml][k=d]) ----
    bf16x8 qf[2][4];
    #pragma unroll
    for (int g = 0; g < 2; ++g)
        #pragma unroll
        for (int k0 = 0; k0 < 4; ++k0)
            qf[g][k0] = *(const bf16x8*)&Qst[rd_off(w * 32 + g * 16 + ml,
                                                    k0 * 32 + quad * 8)];

    float m_i[2] = {-3e38f, -3e38f};
    float l_i[2] = {0.f, 0.f};
    f32x4 o_acc[2][8];
    #pragma unroll
    for (int g = 0; g < 2; ++g)
        #pragma unroll
        for (int dt = 0; dt < 8; ++dt)
            o_acc[g][dt] = (f32x4){0.f, 0.f, 0.f, 0.f};

    const int kmin = (q0 - (WSZ - 1)) > 0 ? (q0 - (WSZ - 1)) : 0;
    const int kb_first = (kmin / BK) * BK;
    const bool sink_extra = (kb_first > 0);
    const int nch = (q0 + BQ - kb_first) / BK + (sink_extra ? 1 : 0);

    const int qrow0 = q0 + w * 32 + ml;         // group 0 q index
    unsigned short* Pw = Ps + w * 2048;         // this wave's P region

    for (int ci = 0; ci < nch; ++ci) {
        const int kb = sink_extra ? (ci == 0 ? 0 : kb_first + (ci - 1) * BK)
                                  : kb_first + ci * BK;

        __syncthreads(); // protects Qst frag reads (ci=0) / prev chunk LDS reads

        // ---- stage K (fp32->bf16, b64 swizzled writes) ----
        #pragma unroll
        for (int i = 0; i < 8; ++i) {
            int idx = tid + i * 256;
            int row = idx >> 5;
            int d0  = (idx & 31) << 2;
            float4 v = *(const float4*)(Kg + baseKV + (size_t)(kb + row) * Dd + d0);
            *(uint2*)&Ks[rd_off(row, d0)] =
                make_uint2(pkbf(v.y, v.x), pkbf(v.w, v.z));
        }
        // ---- stage V transposed: coalesced scalar loads -> b128 writes ----
        {
            int d  = tid & 127;
            int kh = tid >> 7;
            const float* vp = Vg + baseKV + (size_t)(kb + kh * 32) * Dd + d;
            #pragma unroll
            for (int m2 = 0; m2 < 4; ++m2) {
                float e0 = vp[(m2 * 8 + 0) * Dd], e1 = vp[(m2 * 8 + 1) * Dd];
                float e2 = vp[(m2 * 8 + 2) * Dd], e3 = vp[(m2 * 8 + 3) * Dd];
                float e4 = vp[(m2 * 8 + 4) * Dd], e5 = vp[(m2 * 8 + 5) * Dd];
                float e6 = vp[(m2 * 8 + 6) * Dd], e7 = vp[(m2 * 8 + 7) * Dd];
                *(uint4*)&Vts[vt_off(d, kh * 32 + m2 * 8)] =
                    make_uint4(pkbf(e1, e0), pkbf(e3, e2),
                               pkbf(e5, e4), pkbf(e7, e6));
            }
        }
        __syncthreads();

        // ---- S^T = K . Q^T : D[m=key][n=q], 2 groups share K A-frags ----
        f32x4 s[2][4];
        #pragma unroll
        for (int g = 0; g < 2; ++g)
            #pragma unroll
            for (int t = 0; t < 4; ++t)
                s[g][t] = (f32x4){0.f, 0.f, 0.f, 0.f};
        #pragma unroll
        for (int k0 = 0; k0 < 4; ++k0) {
            bf16x8 ka[4];
            #pragma unroll
            for (int t = 0; t < 4; ++t)
                ka[t] = *(const bf16x8*)&Ks[rd_off(t * 16 + ml, k0 * 32 + quad * 8)];
            #pragma unroll
            for (int t = 0; t < 4; ++t) {
                s[0][t] = __builtin_amdgcn_mfma_f32_16x16x32_bf16(ka[t], qf[0][k0], s[0][t], 0, 0, 0);
                s[1][t] = __builtin_amdgcn_mfma_f32_16x16x32_bf16(ka[t], qf[1][k0], s[1][t], 0, 0, 0);
            }
        }

        // fully-in-window chunk? (block-uniform; skips all masking)
        const bool full = (kb + (BK - 1) <= q0) && (kb + (WSZ - BQ) >= q0 - 1);

        #pragma unroll
        for (int g = 0; g < 2; ++g) {
            const int q = qrow0 + g * 16;
            if (!full) {
                #pragma unroll
                for (int t = 0; t < 4; ++t)
                    #pragma unroll
                    for (int r = 0; r < 4; ++r) {
                        int k = kb + t * 16 + quad * 4 + r;
                        bool ok = (k <= q) && ((k + (WSZ - 1) >= q) || (k < NSINK));
                        s[g][t][r] = ok ? s[g][t][r] : -3e38f;
                    }
            }
            // per-lane (q=ml) softmax over own 16 keys, reduce across 4 quads
            float mx = s[g][0][0];
            #pragma unroll
            for (int t = 0; t < 4; ++t)
                #pragma unroll
                for (int r = 0; r < 4; ++r) mx = fmaxf(mx, s[g][t][r]);
            mx = fmaxf(mx, __shfl_xor(mx, 16));
            mx = fmaxf(mx, __shfl_xor(mx, 32));
            const float mnew = fmaxf(m_i[g], mx);
            const float alpha = EXP2(m_i[g] - mnew);
            m_i[g] = mnew;
            float rs = 0.f;
            #pragma unroll
            for (int t = 0; t < 4; ++t)
                #pragma unroll
                for (int r = 0; r < 4; ++r) {
                    float p = EXP2(s[g][t][r] - mnew); // masked -> exact 0
                    s[g][t][r] = p;
                    rs += p;
                }
            rs += __shfl_xor(rs, 16);
            rs += __shfl_xor(rs, 32);
            l_i[g] = alpha * l_i[g] + rs;

            // P store: lane holds 4 consecutive keys per t -> b64 writes
            unsigned short* Pg = Pw + g * 1024;
            #pragma unroll
            for (int t = 0; t < 4; ++t)
                *(uint2*)&Pg[p_off(ml, t * 16 + quad * 4)] =
                    make_uint2(pkbf(s[g][t][1], s[g][t][0]),
                               pkbf(s[g][t][3], s[g][t][2]));
            // rescale O accumulator (alpha per-lane matches O^T q-column)
            #pragma unroll
            for (int dt = 0; dt < 8; ++dt) o_acc[g][dt] *= alpha;
        }

        // ---- O^T += V^T . P^T : 2 groups share Vt A-frags ----
        #pragma unroll
        for (int k0 = 0; k0 < 2; ++k0) {
            bf16x8 pb0 = *(const bf16x8*)&Pw[p_off(ml, k0 * 32 + quad * 8)];
            bf16x8 pb1 = *(const bf16x8*)&Pw[1024 + p_off(ml, k0 * 32 + quad * 8)];
            #pragma unroll
            for (int dt = 0; dt < 8; ++dt) {
                bf16x8 va = *(const bf16x8*)&Vts[vt_off(dt * 16 + ml, k0 * 32 + quad * 8)];
                o_acc[0][dt] = __builtin_amdgcn_mfma_f32_16x16x32_bf16(va, pb0, o_acc[0][dt], 0, 0, 0);
                o_acc[1][dt] = __builtin_amdgcn_mfma_f32_16x16x32_bf16(va, pb1, o_acc[1][dt], 0, 0, 0);
            }
        }
    }

    // ---- epilogue: O[q][d] = O^T / l, vectorized float4 stores ----
    #pragma unroll
    for (int g = 0; g < 2; ++g) {
        const float inv = 1.f / l_i[g];
        float* op = Og + ((size_t)bh * Ld + (qrow0 + g * 16)) * Dd;
        #pragma unroll
        for (int dt = 0; dt < 8; ++dt) {
            float4 o;
            o.x = o_acc[g][dt][0] * inv;
            o.y = o_acc[g][dt][1] * inv;
            o.z = o_acc[g][dt][2] * inv;
            o.w = o_acc[g][dt][3] * inv;
            *(float4*)(op + dt * 16 + quad * 4) = o;
        }
    }
}

extern "C" void kernel_launch(void* const* d_in, const int* in_sizes, int n_in,
                              void* d_out, int out_size, void* d_ws, size_t ws_size,
                              hipStream_t stream) {
    const float* q = (const float*)d_in[0];
    const float* k = (const float*)d_in[1];
    const float* v = (const float*)d_in[2];
    float* o = (float*)d_out;
    const int bhn = in_sizes[0] / (Ld * Dd); // B*H = 32
    dim3 grid(Ld / BQ, bhn);
    swa_fwd<<<grid, dim3(256, 1, 1), 0, stream>>>(q, k, v, o);
}

// Round 3
// 411.235 us; speedup vs baseline: 1.7144x; 1.0404x over previous
//
#include <hip/hip_runtime.h>

constexpr int Ld = 4096;
constexpr int Dd = 128;
constexpr int BQ = 128;
constexpr int BK = 64;
constexpr int WSZ = 2048;
constexpr int NSINK = 4;
// 1/sqrt(128) * log2(e)  (exp2-domain softmax; common factor cancels exactly)
constexpr float QSCALE = 0.08838834764831845f * 1.4426950408889634f;

typedef short bf16x8 __attribute__((ext_vector_type(8)));
typedef float f32x4 __attribute__((ext_vector_type(4)));

#if defined(__has_builtin)
#if __has_builtin(__builtin_amdgcn_exp2f)
#define EXP2(x) __builtin_amdgcn_exp2f(x)
#endif
#endif
#ifndef EXP2
#define EXP2(x) exp2f(x)
#endif

// gfx950 packed fp32->bf16 (RNE): dst[15:0]=bf16(src0), dst[31:16]=bf16(src1)
__device__ __forceinline__ unsigned pkbf(float hi, float lo) {
    unsigned r;
    asm("v_cvt_pk_bf16_f32 %0, %1, %2" : "=v"(r) : "v"(lo), "v"(hi));
    return r;
}

// --- swizzled LDS offsets (ushort units) ---
__device__ __forceinline__ int rd_off(int row, int d) {    // [rows][128]
    return row * 128 + ((((d >> 3) ^ row) & 15) << 3) + (d & 7);
}
__device__ __forceinline__ int vt_off(int drow, int key) { // [128][64] (V^T)
    return drow * 64 + ((((key >> 3) ^ drow) & 7) << 3) + (key & 7);
}
__device__ __forceinline__ int p_off(int row, int key) {   // [16][64], b64-granular
    return row * 64 + ((((key >> 2) ^ ((row & 7) << 1)) & 15) << 2) + (key & 3);
}

__global__ __launch_bounds__(256, 2)
void swa_fwd(const float* __restrict__ Qg, const float* __restrict__ Kg,
             const float* __restrict__ Vg, float* __restrict__ Og) {
    __shared__ __align__(16) unsigned short smem[24576]; // 48 KB
    unsigned short* Ks  = smem;          // [64][128]
    unsigned short* Vts = smem + 8192;   // [128][64]
    unsigned short* Ps  = smem + 16384;  // 4 waves x 2 groups x [16][64]
    unsigned short* Qst = smem;          // [128][128] staging alias (32 KB)

    const int tid  = threadIdx.x;
    const int w    = tid >> 6;
    const int lane = tid & 63;
    const int ml   = lane & 15;
    const int quad = lane >> 4;

    const int qtile = (int)(gridDim.x - 1u - blockIdx.x); // longest first
    const int q0 = qtile * BQ;
    const int bh = blockIdx.y;

    const size_t baseQ  = ((size_t)bh * Ld + q0) * Dd;
    const size_t baseKV = (size_t)bh * Ld * Dd;

    // ---- stage Q (scaled, fp32->bf16) into LDS scratch ----
    #pragma unroll
    for (int i = 0; i < 16; ++i) {
        int idx = tid + i * 256;
        int row = idx >> 5;
        int d0  = (idx & 31) << 2;
        float4 v = *(const float4*)(Qg + baseQ + (size_t)row * Dd + d0);
        *(uint2*)&Qst[rd_off(row, d0)] =
            make_uint2(pkbf(v.y * QSCALE, v.x * QSCALE),
                       pkbf(v.w * QSCALE, v.z * QSCALE));
    }
    __syncthreads();

    // ---- Q B-fragments to registers: qf[group][k0]  (B[n=q=ml][k=d]) ----
    bf16x8 qf[2][4];
    #pragma unroll
    for (int g = 0; g < 2; ++g)
        #pragma unroll
        for (int k0 = 0; k0 < 4; ++k0)
            qf[g][k0] = *(const bf16x8*)&Qst[rd_off(w * 32 + g * 16 + ml,
                                                    k0 * 32 + quad * 8)];

    float m_i[2] = {-3e38f, -3e38f};
    float l_i[2] = {0.f, 0.f};
    f32x4 o_acc[2][8];
    #pragma unroll
    for (int g = 0; g < 2; ++g)
        #pragma unroll
        for (int dt = 0; dt < 8; ++dt)
            o_acc[g][dt] = (f32x4){0.f, 0.f, 0.f, 0.f};

    const int kmin = (q0 - (WSZ - 1)) > 0 ? (q0 - (WSZ - 1)) : 0;
    const int kb_first = (kmin / BK) * BK;
    const bool sink_extra = (kb_first > 0);
    const int nch = (q0 + BQ - kb_first) / BK + (sink_extra ? 1 : 0);

    const int qrow0 = q0 + w * 32 + ml;         // group 0 q index
    unsigned short* Pw = Ps + w * 2048;         // this wave's P region

    // ---- software-pipelined K/V staging: prefetch chunk ci+1 during compute(ci)
    float4 kreg[8];
    float  vreg[32];
    const int kr0 = tid >> 5;          // K row base
    const int kd0 = (tid & 31) << 2;   // K col
    const int vd  = tid & 127;         // V d-index (coalesced)
    const int vkh = tid >> 7;          // V key-half

    auto kvload = [&](int kb) {
        const float* kp = Kg + baseKV + (size_t)(kb + kr0) * Dd + kd0;
        #pragma unroll
        for (int i = 0; i < 8; ++i)
            kreg[i] = *(const float4*)(kp + (size_t)i * 8 * Dd);
        const float* vp = Vg + baseKV + (size_t)(kb + vkh * 32) * Dd + vd;
        #pragma unroll
        for (int j = 0; j < 32; ++j)
            vreg[j] = vp[(size_t)j * Dd];
    };
    auto kb_of = [&](int ci) {
        return sink_extra ? (ci == 0 ? 0 : kb_first + (ci - 1) * BK)
                          : kb_first + ci * BK;
    };

    kvload(kb_of(0));

    for (int ci = 0; ci < nch; ++ci) {
        const int kb = kb_of(ci);

        __syncthreads(); // A: prev chunk's LDS reads (and Qst frag reads) done;
                         //    also drains the prefetch loads (vmcnt0 at barrier)

        // ---- write staged K (registers -> bf16 LDS, swizzled b64) ----
        #pragma unroll
        for (int i = 0; i < 8; ++i)
            *(uint2*)&Ks[rd_off(kr0 + i * 8, kd0)] =
                make_uint2(pkbf(kreg[i].y, kreg[i].x),
                           pkbf(kreg[i].w, kreg[i].z));
        // ---- write staged V transposed (registers -> bf16 LDS, b128) ----
        #pragma unroll
        for (int m2 = 0; m2 < 4; ++m2) {
            *(uint4*)&Vts[vt_off(vd, vkh * 32 + m2 * 8)] =
                make_uint4(pkbf(vreg[m2 * 8 + 1], vreg[m2 * 8 + 0]),
                           pkbf(vreg[m2 * 8 + 3], vreg[m2 * 8 + 2]),
                           pkbf(vreg[m2 * 8 + 5], vreg[m2 * 8 + 4]),
                           pkbf(vreg[m2 * 8 + 7], vreg[m2 * 8 + 6]));
        }
        __syncthreads(); // B: tile visible

        // ---- issue next chunk's global loads; in flight during compute ----
        if (ci + 1 < nch) kvload(kb_of(ci + 1));

        // ---- S^T = K . Q^T : D[m=key][n=q], 2 groups share K A-frags ----
        f32x4 s[2][4];
        #pragma unroll
        for (int g = 0; g < 2; ++g)
            #pragma unroll
            for (int t = 0; t < 4; ++t)
                s[g][t] = (f32x4){0.f, 0.f, 0.f, 0.f};
        #pragma unroll
        for (int k0 = 0; k0 < 4; ++k0) {
            bf16x8 ka[4];
            #pragma unroll
            for (int t = 0; t < 4; ++t)
                ka[t] = *(const bf16x8*)&Ks[rd_off(t * 16 + ml, k0 * 32 + quad * 8)];
            #pragma unroll
            for (int t = 0; t < 4; ++t) {
                s[0][t] = __builtin_amdgcn_mfma_f32_16x16x32_bf16(ka[t], qf[0][k0], s[0][t], 0, 0, 0);
                s[1][t] = __builtin_amdgcn_mfma_f32_16x16x32_bf16(ka[t], qf[1][k0], s[1][t], 0, 0, 0);
            }
        }

        // fully-in-window chunk? (block-uniform; skips all masking)
        const bool full = (kb + (BK - 1) <= q0) && (kb + (WSZ - BQ) >= q0 - 1);

        #pragma unroll
        for (int g = 0; g < 2; ++g) {
            const int q = qrow0 + g * 16;
            if (!full) {
                #pragma unroll
                for (int t = 0; t < 4; ++t)
                    #pragma unroll
                    for (int r = 0; r < 4; ++r) {
                        int k = kb + t * 16 + quad * 4 + r;
                        bool ok = (k <= q) && ((k + (WSZ - 1) >= q) || (k < NSINK));
                        s[g][t][r] = ok ? s[g][t][r] : -3e38f;
                    }
            }
            // per-lane (q=ml) softmax over own 16 keys, reduce across 4 quads
            float mx = s[g][0][0];
            #pragma unroll
            for (int t = 0; t < 4; ++t)
                #pragma unroll
                for (int r = 0; r < 4; ++r) mx = fmaxf(mx, s[g][t][r]);
            mx = fmaxf(mx, __shfl_xor(mx, 16));
            mx = fmaxf(mx, __shfl_xor(mx, 32));
            const float mnew = fmaxf(m_i[g], mx);
            const float alpha = EXP2(m_i[g] - mnew);
            m_i[g] = mnew;
            float rs = 0.f;
            #pragma unroll
            for (int t = 0; t < 4; ++t)
                #pragma unroll
                for (int r = 0; r < 4; ++r) {
                    float p = EXP2(s[g][t][r] - mnew); // masked -> exact 0
                    s[g][t][r] = p;
                    rs += p;
                }
            rs += __shfl_xor(rs, 16);
            rs += __shfl_xor(rs, 32);
            l_i[g] = alpha * l_i[g] + rs;

            // P store: lane holds 4 consecutive keys per t -> b64 writes
            unsigned short* Pg = Pw + g * 1024;
            #pragma unroll
            for (int t = 0; t < 4; ++t)
                *(uint2*)&Pg[p_off(ml, t * 16 + quad * 4)] =
                    make_uint2(pkbf(s[g][t][1], s[g][t][0]),
                               pkbf(s[g][t][3], s[g][t][2]));
            // rescale O accumulator (alpha per-lane matches O^T q-column)
            #pragma unroll
            for (int dt = 0; dt < 8; ++dt) o_acc[g][dt] *= alpha;
        }

        // ---- O^T += V^T . P^T : 2 groups share Vt A-frags ----
        #pragma unroll
        for (int k0 = 0; k0 < 2; ++k0) {
            bf16x8 pb0 = *(const bf16x8*)&Pw[p_off(ml, k0 * 32 + quad * 8)];
            bf16x8 pb1 = *(const bf16x8*)&Pw[1024 + p_off(ml, k0 * 32 + quad * 8)];
            #pragma unroll
            for (int dt = 0; dt < 8; ++dt) {
                bf16x8 va = *(const bf16x8*)&Vts[vt_off(dt * 16 + ml, k0 * 32 + quad * 8)];
                o_acc[0][dt] = __builtin_amdgcn_mfma_f32_16x16x32_bf16(va, pb0, o_acc[0][dt], 0, 0, 0);
                o_acc[1][dt] = __builtin_amdgcn_mfma_f32_16x16x32_bf16(va, pb1, o_acc[1][dt], 0, 0, 0);
            }
        }
    }

    // ---- epilogue: O[q][d] = O^T / l, vectorized float4 stores ----
    #pragma unroll
    for (int g = 0; g < 2; ++g) {
        const float inv = 1.f / l_i[g];
        float* op = Og + ((size_t)bh * Ld + (qrow0 + g * 16)) * Dd;
        #pragma unroll
        for (int dt = 0; dt < 8; ++dt) {
            float4 o;
            o.x = o_acc[g][dt][0] * inv;
            o.y = o_acc[g][dt][1] * inv;
            o.z = o_acc[g][dt][2] * inv;
            o.w = o_acc[g][dt][3] * inv;
            *(float4*)(op + dt * 16 + quad * 4) = o;
        }
    }
}

extern "C" void kernel_launch(void* const* d_in, const int* in_sizes, int n_in,
                              void* d_out, int out_size, void* d_ws, size_t ws_size,
                              hipStream_t stream) {
    const float* q = (const float*)d_in[0];
    const float* k = (const float*)d_in[1];
    const float* v = (const float*)d_in[2];
    float* o = (float*)d_out;
    const int bhn = in_sizes[0] / (Ld * Dd); // B*H = 32
    dim3 grid(Ld / BQ, bhn);
    swa_fwd<<<grid, dim3(256, 1, 1), 0, stream>>>(q, k, v, o);
}